// Round 26
// baseline (151.770 us; speedup 1.0000x reference)
//
#include <hip/hip_runtime.h>
#include <math.h>

#define BB 2
#define LL 2048
#define DIMV 1024
#define SSV 16
#define INNERV 1024
#define E2V 2048
#define MMV (BB*LL)      // 4096 rows
#define NCHUNK 64
#define CLEN 32          // LL / NCHUNK

typedef __attribute__((ext_vector_type(8))) short short8;   // 8 bf16 = 4 VGPRs (MFMA A/B frag)
typedef __attribute__((ext_vector_type(4))) float f32x4;    // MFMA C/D frag

static __device__ __forceinline__ float4 ld4(const float* p){
  return *reinterpret_cast<const float4*>(p);
}
// RNE fp32 -> bf16 (bit-level)
static __device__ __forceinline__ ushort f2bf(float x){
  unsigned u = __float_as_uint(x);
  unsigned r = (u + 0x7fffu + ((u >> 16) & 1u)) >> 16;
  return (ushort)r;
}
static __device__ __forceinline__ float bf2f(ushort h){
  return __uint_as_float(((unsigned)h) << 16);
}
// async global->LDS, 16B per lane; lds dest wave-uniform base + lane*16
static __device__ __forceinline__ void gld16(const void* g, void* l){
  __builtin_amdgcn_global_load_lds(
      (const __attribute__((address_space(1))) void*)g,
      (__attribute__((address_space(3))) void*)l, 16, 0, 0);
}

// Bijective XCD-aware swizzle (m204 form): each XCD owns a contiguous chunk
// of wgids (= whole A row-panels). R20->R21 A/B: -9.3 us.
static __device__ __forceinline__ int xcd_swz2(){
  int bid = blockIdx.y * gridDim.x + blockIdx.x;
  int nwg = gridDim.x * gridDim.y;
  int q = nwg >> 3, r = nwg & 7;
  int xcd = bid & 7, idx = bid >> 3;
  return (xcd < r ? xcd*(q+1) : r*(q+1) + (xcd - r)*q) + idx;
}

// ---------- fused init (weight casts incl. Wcat build) + LayerNorm ----------
__global__ __launch_bounds__(256) void ln_init(
        const float* __restrict__ x, const float* __restrict__ gamma,
        const float* __restrict__ beta, ushort* __restrict__ hh,
        const float* __restrict__ W_in, const float* __restrict__ W_dt,
        const float* __restrict__ W_out, const float* __restrict__ wx,
        ushort* __restrict__ Wih, ushort* __restrict__ Wch,
        ushort* __restrict__ Woh){
  __shared__ float red[8];
  if (blockIdx.x < 4224){
    int idx = blockIdx.x*256 + threadIdx.x;
    if (idx < 1032*1024){
      const float* src; ushort* dst; int i;
      if (idx < 512*1024){ src = W_in;  dst = Wih; i = idx; }
      else if (idx < 768*1024){ src = W_dt;  dst = Wch; i = idx - 512*1024; }
      else if (idx < 1024*1024){ src = W_out; dst = Woh; i = idx - 768*1024; }
      else { src = wx; dst = Wch + (size_t)1024*1024; i = idx - 1024*1024; }
      float4 v = ld4(src + (size_t)i*4);
      ushort4 H;
      H.x=f2bf(v.x); H.y=f2bf(v.y); H.z=f2bf(v.z); H.w=f2bf(v.w);
      *reinterpret_cast<ushort4*>(dst + (size_t)i*4) = H;
    } else {
      int i = idx - 1032*1024;           // [0, 24576): zero rows 1056..1151
      *reinterpret_cast<ushort4*>(Wch + (size_t)1056*1024 + (size_t)i*4) =
          make_ushort4(0,0,0,0);
    }
    return;
  }
  int row = blockIdx.x - 4224;
  int tid = threadIdx.x;
  const float* xr = x + (size_t)row*DIMV;
  float4 v = ld4(xr + tid*4);
  float s  = v.x+v.y+v.z+v.w;
  float s2 = v.x*v.x+v.y*v.y+v.z*v.z+v.w*v.w;
  for (int o=32;o;o>>=1){ s += __shfl_down(s,o); s2 += __shfl_down(s2,o); }
  int wid = tid>>6, lane = tid&63;
  if (lane==0){ red[wid]=s; red[4+wid]=s2; }
  __syncthreads();
  s  = red[0]+red[1]+red[2]+red[3];
  s2 = red[4]+red[5]+red[6]+red[7];
  float mu  = s*(1.f/DIMV);
  float var = s2*(1.f/DIMV) - mu*mu;
  float rstd = rsqrtf(var + 1e-5f);
  float4 g = ld4(gamma + tid*4), be = ld4(beta + tid*4);
  ushort4 H;
  H.x = f2bf((v.x-mu)*rstd*g.x + be.x);
  H.y = f2bf((v.y-mu)*rstd*g.y + be.y);
  H.z = f2bf((v.z-mu)*rstd*g.z + be.z);
  H.w = f2bf((v.w-mu)*rstd*g.w + be.w);
  *reinterpret_cast<ushort4*>(hh + (size_t)row*DIMV + tid*4) = H;
}

// ============ bf16 MFMA GEMM body: Co[M,N] = A[M,1024]*Bw[N,1024]^T ============
// COUNTED-VMCNT TRIPLE-buffer (T3+T4, depth 3): prefetch distance = 2 compute
// phases (~800+cy) to actually cover L2/HBM latency (2-deep was null, R25:
// distance ~1 phase < ~600-900cy latency). Invariants unchanged from the
// R25-verified counted template: STAGE = exactly 4 loads/thread; per tile i:
//   s_waitcnt vmcnt(8)  (12 outstanding -> oldest 4 = tile i done)
//   s_barrier           (all waves' waits passed => buffer globally ready)
//   ds_read + MFMA
//   s_waitcnt lgkmcnt(0); s_barrier   (reads retired before restage)
//   restage buffer i%3 with tile i+3
// Tails peel at vmcnt(8)/(4)/(0). BM=BN=BK=64; 48KB LDS (3 x 16KB);
// 4 waves 2m x 2n; wave tile 32x32. LDS rows 128B = 8x16B units, XOR swizzle
// unit^=(row&7); staged via inverse-swizzled global source (k16=(t&7)^(rr&7)),
// read with same XOR.
#define GBK 64
#define NKT 16

#define WAITV8 asm volatile("s_waitcnt vmcnt(8)" ::: "memory")
#define WAITV4 asm volatile("s_waitcnt vmcnt(4)" ::: "memory")
#define WAITV0 asm volatile("s_waitcnt vmcnt(0)" ::: "memory")
#define WAITL0 asm volatile("s_waitcnt lgkmcnt(0)" ::: "memory")

template<int EPI>
static __device__ __forceinline__ void gemm_body(ushort* lds,
    const ushort* __restrict__ A, const ushort* __restrict__ Bw,
    void* __restrict__ Co_, int N, const float* __restrict__ aux,
    float* __restrict__ aux2, int bm, int bn){
  const int t  = threadIdx.x;
  const int rr  = t >> 3;                 // 0..31: row within a 32-row chunk
  const int k16 = (t & 7) ^ (rr & 7);     // logical 16B unit fetched
  const ushort* gA = A  + (size_t)(bm + rr)*1024 + k16*8;
  const ushort* gB = Bw + (size_t)(bn + rr)*1024 + k16*8;
  const int wofs = (t >> 6) * 1024;       // wave offset inside a 4KB chunk

  const int l  = t & 63, wv = t >> 6;
  const int wm = wv & 1, wn = wv >> 1;    // 2m x 2n waves, 32x32 tiles
  const int fr = l & 15, kb = l >> 4;

  f32x4 acc[2][2];
  #pragma unroll
  for (int m=0;m<2;m++){
    #pragma unroll
    for (int n=0;n<2;n++) acc[m][n] = (f32x4){0.f,0.f,0.f,0.f};
  }

  #define STAGE_T(base, kt_) { \
    const int ko = (kt_)*GBK; \
    gld16(gA + ko,           (base) +     0 + wofs); \
    gld16(gA + ko + 32*1024, (base) +  4096 + wofs); \
    gld16(gB + ko,           (base) +  8192 + wofs); \
    gld16(gB + ko + 32*1024, (base) + 12288 + wofs); }

  #define COMPUTE_T(base) { \
    short8 a[2][2], b[2][2]; \
    _Pragma("unroll") \
    for (int m=0;m<2;m++){ \
      int row = wm*32 + m*16 + fr; \
      _Pragma("unroll") \
      for (int ks=0;ks<2;ks++) \
        a[m][ks] = *(const short8*)((base) + row*128 + (((ks*4+kb)^(fr&7))*16)); \
    } \
    _Pragma("unroll") \
    for (int n=0;n<2;n++){ \
      int row = wn*32 + n*16 + fr; \
      _Pragma("unroll") \
      for (int ks=0;ks<2;ks++) \
        b[n][ks] = *(const short8*)((base) + 8192 + row*128 + (((ks*4+kb)^(fr&7))*16)); \
    } \
    _Pragma("unroll") \
    for (int ks=0;ks<2;ks++){ \
      _Pragma("unroll") \
      for (int m=0;m<2;m++){ \
        _Pragma("unroll") \
        for (int n=0;n<2;n++) \
          acc[m][n] = __builtin_amdgcn_mfma_f32_16x16x32_bf16(a[m][ks], b[n][ks], acc[m][n], 0,0,0); \
      } \
    } }

  char* L0 = (char*)lds;
  STAGE_T(L0,           0);              //  4 outstanding
  STAGE_T(L0 + 16384,   1);              //  8 outstanding
  STAGE_T(L0 + 32768,   2);              // 12 outstanding
  // main loop: i = 0..12 — compute tile i (buffer i%3), restage tile i+3
  #pragma unroll 1
  for (int i = 0; i < NKT-3; ++i){
    char* base = L0 + (i%3)*16384;
    WAITV8;                              // tile i's 4 loads done (12 -> 8)
    __builtin_amdgcn_s_barrier();
    COMPUTE_T(base);
    WAITL0;
    __builtin_amdgcn_s_barrier();        // all reads of this buffer retired
    STAGE_T(base, i+3);                  // back to 12 outstanding
  }
  // tails: i = 13 (buf 1), 14 (buf 2), 15 (buf 0); no restage
  {
    char* base = L0 + 1*16384;           // 13%3 = 1
    WAITV8;                              // tile 13 done (12 -> 8)
    __builtin_amdgcn_s_barrier();
    COMPUTE_T(base);
  }
  {
    char* base = L0 + 2*16384;           // 14%3 = 2
    WAITV4;                              // tile 14 done (8 -> 4)
    __builtin_amdgcn_s_barrier();
    COMPUTE_T(base);
  }
  {
    char* base = L0;                     // 15%3 = 0
    WAITV0;                              // tile 15 done
    __builtin_amdgcn_s_barrier();
    COMPUTE_T(base);
  }
  #undef STAGE_T
  #undef COMPUTE_T

  // C/D layout: col = lane&15, row = (lane>>4)*4 + reg   [m89-verified]
  #pragma unroll
  for (int m=0;m<2;m++){
    int row0 = bm + wm*32 + m*16 + kb*4;
    #pragma unroll
    for (int n=0;n<2;n++){
      int col = bn + wn*32 + n*16 + fr;
      #pragma unroll
      for (int j=0;j<4;j++){
        int r = row0 + j;
        float v = acc[m][n][j];
        if (EPI==0){
          ((ushort*)Co_)[(size_t)r*N + col] = f2bf(v);
        } else if (EPI==2){
          v += aux[(size_t)r*N + col];
          ((float*)Co_)[(size_t)r*N + col] = v;
        } else {  // EPI==3
          if (col < 1024){
            v += aux[col];
            v = (v > 20.f) ? v : log1pf(__expf(v));
            ((ushort*)Co_)[(size_t)r*1024 + col] = f2bf(v);
          } else if (col < 1056){
            aux2[(size_t)r*32 + (col - 1024)] = v;
          }
        }
      }
    }
  }
}

template<int EPI>
__global__ __launch_bounds__(256, 3) void gemm_bf16(
    const ushort* __restrict__ A, const ushort* __restrict__ Bw,
    void* __restrict__ Co_, int N, const float* __restrict__ aux){
  __shared__ __align__(16) ushort lds[24576];   // 48KB: 3 x 16KB
  int wg = xcd_swz2();
  int row = wg / gridDim.x, col = wg % gridDim.x;
  gemm_body<EPI>(lds, A, Bw, Co_, N, aux, nullptr, row*64, col*64);
}

// ------- dt||BC combined GEMM: xc @ Wcat^T, Wcat = [W_dt;W_x;pad] (1152 rows) -------
__global__ __launch_bounds__(256, 3) void gemm_dtbc(
    const ushort* __restrict__ xch, const ushort* __restrict__ Wch,
    ushort* __restrict__ dtb, const float* __restrict__ b_dt,
    float* __restrict__ bcb){
  __shared__ __align__(16) ushort lds[24576];
  int wg = xcd_swz2();
  int row = wg / gridDim.x, col = wg % gridDim.x;
  gemm_body<3>(lds, xch, Wch, dtb, 1024, b_dt, bcb, row*64, col*64);
}

// ---------------- depthwise conv(K=3,pad=1) + silu -> bf16 ----------------
__global__ __launch_bounds__(256) void conv_silu_kernel(const ushort* __restrict__ xz,
        const float* __restrict__ cw, ushort* __restrict__ xch){
  int idx = blockIdx.x*256 + threadIdx.x;
  int d4  = idx & 255;
  int row = idx >> 8;
  int t = row & (LL-1);
  const ushort* p = xz + (size_t)row*E2V + d4*4;
  ushort4 u1 = *reinterpret_cast<const ushort4*>(p);
  ushort4 u0 = (t>0)    ? *reinterpret_cast<const ushort4*>(p - E2V) : make_ushort4(0,0,0,0);
  ushort4 u2 = (t<LL-1) ? *reinterpret_cast<const ushort4*>(p + E2V) : make_ushort4(0,0,0,0);
  int d = d4*4;
  float w[12];
  #pragma unroll
  for (int i=0;i<12;i++) w[i] = cw[d*3 + i];
  float4 o;
  o.x = bf2f(u0.x)*w[0] + bf2f(u1.x)*w[1]  + bf2f(u2.x)*w[2];
  o.y = bf2f(u0.y)*w[3] + bf2f(u1.y)*w[4]  + bf2f(u2.y)*w[5];
  o.z = bf2f(u0.z)*w[6] + bf2f(u1.z)*w[7]  + bf2f(u2.z)*w[8];
  o.w = bf2f(u0.w)*w[9] + bf2f(u1.w)*w[10] + bf2f(u2.w)*w[11];
  o.x = o.x / (1.f + __expf(-o.x));
  o.y = o.y / (1.f + __expf(-o.y));
  o.z = o.z / (1.f + __expf(-o.z));
  o.w = o.w / (1.f + __expf(-o.w));
  ushort4 H;
  H.x=f2bf(o.x); H.y=f2bf(o.y); H.z=f2bf(o.z); H.w=f2bf(o.w);
  *reinterpret_cast<ushort4*>(xch + (size_t)row*DIMV + d4*4) = H;
}

// ======== scan, one thread per channel d; S=16 state in registers ========
__global__ __launch_bounds__(256) void scan_p1(const ushort* __restrict__ dt,
        const float* __restrict__ bc, const float* __restrict__ A_log,
        ushort* __restrict__ F, ushort* __restrict__ P){
  __shared__ float sB[CLEN*32];
  int bid = blockIdx.x;                 // b*(NCHUNK*4) + c*4 + dblk
  int dblk = bid & 3;
  int c  = (bid >> 2) & (NCHUNK-1);
  int b  = bid >> 8;
  int tid = threadIdx.x;
  int d = dblk*256 + tid;
  int row0 = b*LL + c*CLEN;
  ((float4*)sB)[tid] = *((const float4*)(bc + (size_t)row0*32) + tid);
  float a[16];
  {
    const float4* ap = (const float4*)(A_log + d*16);
    #pragma unroll
    for (int q=0;q<4;q++){
      float4 v = ap[q];
      a[q*4+0]=-__expf(v.x); a[q*4+1]=-__expf(v.y);
      a[q*4+2]=-__expf(v.z); a[q*4+3]=-__expf(v.w);
    }
  }
  __syncthreads();
  float st[16];
  #pragma unroll
  for (int s=0;s<16;s++) st[s]=0.f;
  float sdt = 0.f;
  const ushort* dtp = dt + (size_t)row0*DIMV + d;
  for (int t=0;t<CLEN;t++){
    float dtv = bf2f(dtp[(size_t)t*DIMV]);
    sdt += dtv;
    float4 B0 = *(const float4*)&sB[t*32+0];
    float4 B1 = *(const float4*)&sB[t*32+4];
    float4 B2 = *(const float4*)&sB[t*32+8];
    float4 B3 = *(const float4*)&sB[t*32+12];
    float Bv[16] = {B0.x,B0.y,B0.z,B0.w,B1.x,B1.y,B1.z,B1.w,
                    B2.x,B2.y,B2.z,B2.w,B3.x,B3.y,B3.z,B3.w};
    #pragma unroll
    for (int s=0;s<16;s++){
      float dA = __expf(dtv*a[s]);
      st[s] = fmaf(st[s], dA, dtv*Bv[s]);
    }
  }
  size_t o = ((size_t)((b*NCHUNK + c)*DIMV + d))*16;
  #pragma unroll
  for (int q=0;q<4;q++){
    ushort4 fv, pv;
    fv.x=f2bf(st[q*4]);   fv.y=f2bf(st[q*4+1]);
    fv.z=f2bf(st[q*4+2]); fv.w=f2bf(st[q*4+3]);
    pv.x=f2bf(__expf(sdt*a[q*4]));   pv.y=f2bf(__expf(sdt*a[q*4+1]));
    pv.z=f2bf(__expf(sdt*a[q*4+2])); pv.w=f2bf(__expf(sdt*a[q*4+3]));
    *(ushort4*)(F + o + q*4) = fv;
    *(ushort4*)(P + o + q*4) = pv;
  }
}

__global__ __launch_bounds__(256) void scan_p2(const ushort* __restrict__ F,
        const ushort* __restrict__ P, ushort* __restrict__ E){
  int idx = blockIdx.x*256 + threadIdx.x;   // BB*DIMV*SSV = 32768
  int b  = idx >> 14;
  int ds = idx & 16383;
  float e = 0.f;
  for (int c=0;c<NCHUNK;c++){
    size_t o = ((size_t)(b*NCHUNK + c) << 14) + ds;
    E[o] = f2bf(e);
    e = fmaf(bf2f(P[o]), e, bf2f(F[o]));
  }
}

__global__ __launch_bounds__(256) void scan_p3(const ushort* __restrict__ dt,
        const float* __restrict__ bc, const float* __restrict__ A_log,
        const ushort* __restrict__ E, const ushort* __restrict__ xch,
        const ushort* __restrict__ xz, const float* __restrict__ Dp,
        ushort* __restrict__ yh){
  __shared__ float sBC[CLEN*32];
  int bid = blockIdx.x;
  int dblk = bid & 3;
  int c  = (bid >> 2) & (NCHUNK-1);
  int b  = bid >> 8;
  int tid = threadIdx.x;
  int d = dblk*256 + tid;
  int row0 = b*LL + c*CLEN;
  ((float4*)sBC)[tid] = *((const float4*)(bc + (size_t)row0*32) + tid);
  float a[16];
  {
    const float4* ap = (const float4*)(A_log + d*16);
    #pragma unroll
    for (int q=0;q<4;q++){
      float4 v = ap[q];
      a[q*4+0]=-__expf(v.x); a[q*4+1]=-__expf(v.y);
      a[q*4+2]=-__expf(v.z); a[q*4+3]=-__expf(v.w);
    }
  }
  float st[16];
  {
    size_t o = ((size_t)((b*NCHUNK + c)*DIMV + d))*16;
    #pragma unroll
    for (int q=0;q<4;q++){
      ushort4 v = *(const ushort4*)(E + o + q*4);
      st[q*4]=bf2f(v.x); st[q*4+1]=bf2f(v.y); st[q*4+2]=bf2f(v.z); st[q*4+3]=bf2f(v.w);
    }
  }
  float Dv = Dp[d];
  __syncthreads();
  const ushort* dtp = dt + (size_t)row0*DIMV + d;
  for (int t=0;t<CLEN;t++){
    float dtv = bf2f(dtp[(size_t)t*DIMV]);
    float4 B0 = *(const float4*)&sBC[t*32+0];
    float4 B1 = *(const float4*)&sBC[t*32+4];
    float4 B2 = *(const float4*)&sBC[t*32+8];
    float4 B3 = *(const float4*)&sBC[t*32+12];
    float4 C0 = *(const float4*)&sBC[t*32+16];
    float4 C1 = *(const float4*)&sBC[t*32+20];
    float4 C2 = *(const float4*)&sBC[t*32+24];
    float4 C3 = *(const float4*)&sBC[t*32+28];
    float Bv[16] = {B0.x,B0.y,B0.z,B0.w,B1.x,B1.y,B1.z,B1.w,
                    B2.x,B2.y,B2.z,B2.w,B3.x,B3.y,B3.z,B3.w};
    float Cv[16] = {C0.x,C0.y,C0.z,C0.w,C1.x,C1.y,C1.z,C1.w,
                    C2.x,C2.y,C2.z,C2.w,C3.x,C3.y,C3.z,C3.w};
    float y = 0.f;
    #pragma unroll
    for (int s=0;s<16;s++){
      float dA = __expf(dtv*a[s]);
      st[s] = fmaf(st[s], dA, dtv*Bv[s]);
      y = fmaf(st[s], Cv[s], y);
    }
    int row = row0 + t;
    size_t ofs = (size_t)row*DIMV + d;
    float xcv = bf2f(xch[ofs]);
    float zv  = bf2f(xz[(size_t)row*E2V + INNERV + d]);
    float sz  = zv / (1.f + __expf(-zv));
    yh[ofs] = f2bf((y + Dv*xcv)*sz);
  }
}

extern "C" void kernel_launch(void* const* d_in, const int* in_sizes, int n_in,
                              void* d_out, int out_size, void* d_ws, size_t ws_size,
                              hipStream_t stream){
  const float* x     = (const float*)d_in[0];
  const float* gamma = (const float*)d_in[1];
  const float* beta  = (const float*)d_in[2];
  const float* W_in  = (const float*)d_in[3];
  const float* cw    = (const float*)d_in[4];
  const float* W_x   = (const float*)d_in[5];
  const float* W_dt  = (const float*)d_in[6];
  const float* b_dt  = (const float*)d_in[7];
  const float* A_log = (const float*)d_in[8];
  const float* Dp    = (const float*)d_in[9];
  const float* W_out = (const float*)d_in[10];
  float* out = (float*)d_out;
  float* ws  = (float*)d_ws;
  const size_t MB = (size_t)1 << 20;   // 1M floats
  // layout (float units); bf16 buffer of N elems occupies N/2 float slots.
  ushort* xzh = (ushort*)ws;                      // 8M bf16 -> [0,4M)
  ushort* hh  = (ushort*)(ws + 4*MB);             // [4M,6M)  dead after gemm0
  ushort* yh  = (ushort*)(ws + 4*MB);             // p3 writes (hh dead)
  ushort* xch = (ushort*)(ws + 6*MB);             // [6M,8M)
  ushort* dtb = (ushort*)(ws + 8*MB);             // [8M,10M)
  ushort* F   = (ushort*)(ws + 10*MB);            // [10M,11M)
  ushort* P   = (ushort*)(ws + 11*MB);            // [11M,12M)
  ushort* E   = (ushort*)(ws + 12*MB);            // [12M,13M)
  ushort* Wih = (ushort*)(ws + 13*MB);            // [13M,14M)  2M ushorts
  ushort* Wch = (ushort*)(ws + 14*MB);            // [14M,14.6M) 1152x1024 ushorts
  ushort* Woh = (ushort*)(ws + 14*MB + 640*1024); // [14.625M,15.125M)
  float*  bcb = ws + 15*MB + 256*1024;            // [15.25M, +128K floats)

  ln_init<<<4224 + MMV, 256, 0, stream>>>(x, gamma, beta, hh,
                                          W_in, W_dt, W_out, W_x,
                                          Wih, Wch, Woh);
  gemm_bf16<0><<<dim3(E2V/64, MMV/64), 256, 0, stream>>>(hh, Wih, xzh, E2V, nullptr);
  conv_silu_kernel<<<(MMV*(DIMV/4))/256, 256, 0, stream>>>(xzh, cw, xch);
  gemm_dtbc<<<dim3(17, MMV/64), 256, 0, stream>>>(xch, Wch, dtb, b_dt, bcb);
  scan_p1<<<BB*NCHUNK*(DIMV/256), 256, 0, stream>>>(dtb, bcb, A_log, F, P);
  scan_p2<<<(BB*DIMV*SSV)/256, 256, 0, stream>>>(F, P, E);
  scan_p3<<<BB*NCHUNK*(DIMV/256), 256, 0, stream>>>(dtb, bcb, A_log, E, xch, xzh, Dp, yh);
  gemm_bf16<2><<<dim3(DIMV/64, MMV/64), 256, 0, stream>>>(yh, Woh, out, DIMV, x);
}

// Round 27
// 147.061 us; speedup vs baseline: 1.0320x; 1.0320x over previous
//
#include <hip/hip_runtime.h>
#include <math.h>

#define BB 2
#define LL 2048
#define DIMV 1024
#define SSV 16
#define INNERV 1024
#define E2V 2048
#define MMV (BB*LL)      // 4096 rows
#define NCHUNK 64
#define CLEN 32          // LL / NCHUNK

typedef __attribute__((ext_vector_type(8))) short short8;   // 8 bf16 = 4 VGPRs (MFMA A/B frag)
typedef __attribute__((ext_vector_type(4))) float f32x4;    // MFMA C/D frag

static __device__ __forceinline__ float4 ld4(const float* p){
  return *reinterpret_cast<const float4*>(p);
}
// RNE fp32 -> bf16 (bit-level)
static __device__ __forceinline__ ushort f2bf(float x){
  unsigned u = __float_as_uint(x);
  unsigned r = (u + 0x7fffu + ((u >> 16) & 1u)) >> 16;
  return (ushort)r;
}
static __device__ __forceinline__ float bf2f(ushort h){
  return __uint_as_float(((unsigned)h) << 16);
}
// async global->LDS, 16B per lane; lds dest wave-uniform base + lane*16
static __device__ __forceinline__ void gld16(const void* g, void* l){
  __builtin_amdgcn_global_load_lds(
      (const __attribute__((address_space(1))) void*)g,
      (__attribute__((address_space(3))) void*)l, 16, 0, 0);
}

// Bijective XCD-aware swizzle (m204 form). Grids here are %8==0 (r==0).
// Maps flat bid -> wgid so each XCD owns a CONTIGUOUS chunk of wgids
// (= whole A row-panels) -> A panels fetched by exactly one XCD L2.
static __device__ __forceinline__ int xcd_swz(){
  int bid = blockIdx.y * gridDim.x + blockIdx.x;
  int nwg = gridDim.x * gridDim.y;
  int q = nwg >> 3, r = nwg & 7;
  int xcd = bid & 7, idx = bid >> 3;
  return (xcd < r ? xcd*(q+1) : r*(q+1) + (xcd - r)*q) + idx;
}

// ---------- fused init (weight casts incl. Wcat build) + LayerNorm ----------
__global__ __launch_bounds__(256) void ln_init(
        const float* __restrict__ x, const float* __restrict__ gamma,
        const float* __restrict__ beta, ushort* __restrict__ hh,
        const float* __restrict__ W_in, const float* __restrict__ W_dt,
        const float* __restrict__ W_out, const float* __restrict__ wx,
        ushort* __restrict__ Wih, ushort* __restrict__ Wch,
        ushort* __restrict__ Woh){
  __shared__ float red[8];
  if (blockIdx.x < 4224){
    int idx = blockIdx.x*256 + threadIdx.x;
    if (idx < 1032*1024){
      const float* src; ushort* dst; int i;
      if (idx < 512*1024){ src = W_in;  dst = Wih; i = idx; }
      else if (idx < 768*1024){ src = W_dt;  dst = Wch; i = idx - 512*1024; }
      else if (idx < 1024*1024){ src = W_out; dst = Woh; i = idx - 768*1024; }
      else { src = wx; dst = Wch + (size_t)1024*1024; i = idx - 1024*1024; }
      float4 v = ld4(src + (size_t)i*4);
      ushort4 H;
      H.x=f2bf(v.x); H.y=f2bf(v.y); H.z=f2bf(v.z); H.w=f2bf(v.w);
      *reinterpret_cast<ushort4*>(dst + (size_t)i*4) = H;
    } else {
      int i = idx - 1032*1024;           // [0, 24576): zero rows 1056..1151
      *reinterpret_cast<ushort4*>(Wch + (size_t)1056*1024 + (size_t)i*4) =
          make_ushort4(0,0,0,0);
    }
    return;
  }
  int row = blockIdx.x - 4224;
  int tid = threadIdx.x;
  const float* xr = x + (size_t)row*DIMV;
  float4 v = ld4(xr + tid*4);
  float s  = v.x+v.y+v.z+v.w;
  float s2 = v.x*v.x+v.y*v.y+v.z*v.z+v.w*v.w;
  for (int o=32;o;o>>=1){ s += __shfl_down(s,o); s2 += __shfl_down(s2,o); }
  int wid = tid>>6, lane = tid&63;
  if (lane==0){ red[wid]=s; red[4+wid]=s2; }
  __syncthreads();
  s  = red[0]+red[1]+red[2]+red[3];
  s2 = red[4]+red[5]+red[6]+red[7];
  float mu  = s*(1.f/DIMV);
  float var = s2*(1.f/DIMV) - mu*mu;
  float rstd = rsqrtf(var + 1e-5f);
  float4 g = ld4(gamma + tid*4), be = ld4(beta + tid*4);
  ushort4 H;
  H.x = f2bf((v.x-mu)*rstd*g.x + be.x);
  H.y = f2bf((v.y-mu)*rstd*g.y + be.y);
  H.z = f2bf((v.z-mu)*rstd*g.z + be.z);
  H.w = f2bf((v.w-mu)*rstd*g.w + be.w);
  *reinterpret_cast<ushort4*>(hh + (size_t)row*DIMV + tid*4) = H;
}

// ============ bf16 MFMA GEMM body: Co[M,N] = A[M,1024]*Bw[N,1024]^T ============
// 2-PHASE double-buffered pipeline; one __syncthreads per K-step.
// BM=64, BN=64, BK=64; 32KB LDS (2 x 16KB); 4 waves 2m x 2n; wave tile 32x32.
// LDS rows 128B = 8x16B units, XOR swizzle unit^=(row&7); staged via
// inverse-swizzled global source (k16=(t&7)^(rr&7)), read with same XOR.
// EPI 0: bf16 store. EPI 2: +aux[row*N+col], fp32 store.
// EPI 3: split — col<1024: softplus(+aux[col]) bf16 -> Co_ (stride 1024);
//        1024<=col<1056: fp32 -> aux2[row*32+col-1024]; col>=1056: discard.
#define GBK 64
#define NKT 16

template<int EPI>
static __device__ __forceinline__ void gemm_body(ushort* lds,
    const ushort* __restrict__ A, const ushort* __restrict__ Bw,
    void* __restrict__ Co_, int N, const float* __restrict__ aux,
    float* __restrict__ aux2, int bm, int bn){
  const int t  = threadIdx.x;
  const int rr  = t >> 3;                 // 0..31: row within a 32-row chunk
  const int k16 = (t & 7) ^ (rr & 7);     // logical 16B unit fetched
  const ushort* gA = A  + (size_t)(bm + rr)*1024 + k16*8;
  const ushort* gB = Bw + (size_t)(bn + rr)*1024 + k16*8;
  const int wofs = (t >> 6) * 1024;       // wave offset inside a 4KB chunk

  const int l  = t & 63, wv = t >> 6;
  const int wm = wv & 1, wn = wv >> 1;    // 2m x 2n waves, 32x32 tiles
  const int fr = l & 15, kb = l >> 4;

  f32x4 acc[2][2];
  #pragma unroll
  for (int m=0;m<2;m++){
    #pragma unroll
    for (int n=0;n<2;n++) acc[m][n] = (f32x4){0.f,0.f,0.f,0.f};
  }

  char* Lb0 = (char*)lds;            // buffer 0
  char* Lb1 = (char*)lds + 16384;    // buffer 1

  #define STAGE_T(base, kt_) { \
    const int ko = (kt_)*GBK; \
    gld16(gA + ko,           (base) +     0 + wofs); \
    gld16(gA + ko + 32*1024, (base) +  4096 + wofs); \
    gld16(gB + ko,           (base) +  8192 + wofs); \
    gld16(gB + ko + 32*1024, (base) + 12288 + wofs); }

  #define COMPUTE_T(base) { \
    short8 a[2][2], b[2][2]; \
    _Pragma("unroll") \
    for (int m=0;m<2;m++){ \
      int row = wm*32 + m*16 + fr; \
      _Pragma("unroll") \
      for (int ks=0;ks<2;ks++) \
        a[m][ks] = *(const short8*)((base) + row*128 + (((ks*4+kb)^(fr&7))*16)); \
    } \
    _Pragma("unroll") \
    for (int n=0;n<2;n++){ \
      int row = wn*32 + n*16 + fr; \
      _Pragma("unroll") \
      for (int ks=0;ks<2;ks++) \
        b[n][ks] = *(const short8*)((base) + 8192 + row*128 + (((ks*4+kb)^(fr&7))*16)); \
    } \
    _Pragma("unroll") \
    for (int ks=0;ks<2;ks++){ \
      _Pragma("unroll") \
      for (int m=0;m<2;m++){ \
        _Pragma("unroll") \
        for (int n=0;n<2;n++) \
          acc[m][n] = __builtin_amdgcn_mfma_f32_16x16x32_bf16(a[m][ks], b[n][ks], acc[m][n], 0,0,0); \
      } \
    } }

  STAGE_T(Lb0, 0);
  __syncthreads();                       // buf0 ready
  #pragma unroll 1
  for (int kt = 0; kt < NKT; kt += 2){
    if (kt+1 < NKT) STAGE_T(Lb1, kt+1);
    COMPUTE_T(Lb0);
    __syncthreads();                     // buf1 ready; buf0 reads retired
    if (kt+1 < NKT){
      if (kt+2 < NKT) STAGE_T(Lb0, kt+2);
      COMPUTE_T(Lb1);
      __syncthreads();                   // buf0 ready; buf1 reads retired
    }
  }
  #undef STAGE_T
  #undef COMPUTE_T

  // C/D layout: col = lane&15, row = (lane>>4)*4 + reg   [m89-verified]
  #pragma unroll
  for (int m=0;m<2;m++){
    int row0 = bm + wm*32 + m*16 + kb*4;
    #pragma unroll
    for (int n=0;n<2;n++){
      int col = bn + wn*32 + n*16 + fr;
      #pragma unroll
      for (int j=0;j<4;j++){
        int r = row0 + j;
        float v = acc[m][n][j];
        if (EPI==0){
          ((ushort*)Co_)[(size_t)r*N + col] = f2bf(v);
        } else if (EPI==2){
          v += aux[(size_t)r*N + col];
          ((float*)Co_)[(size_t)r*N + col] = v;
        } else {  // EPI==3
          if (col < 1024){
            v += aux[col];
            v = (v > 20.f) ? v : log1pf(__expf(v));
            ((ushort*)Co_)[(size_t)r*1024 + col] = f2bf(v);
          } else if (col < 1056){
            aux2[(size_t)r*32 + (col - 1024)] = v;
          }
        }
      }
    }
  }
}

template<int EPI>
__global__ __launch_bounds__(256, 4) void gemm_bf16(
    const ushort* __restrict__ A, const ushort* __restrict__ Bw,
    void* __restrict__ Co_, int N, const float* __restrict__ aux){
  __shared__ __align__(16) ushort lds[16384];   // 32KB: 2 x 16KB buffers
  int wg = xcd_swz();
  int row = wg / gridDim.x, col = wg % gridDim.x;
  gemm_body<EPI>(lds, A, Bw, Co_, N, aux, nullptr, row*64, col*64);
}

// ------- dt||BC combined GEMM: xc @ Wcat^T, Wcat = [W_dt;W_x;pad] (1152 rows) -------
__global__ __launch_bounds__(256, 4) void gemm_dtbc(
    const ushort* __restrict__ xch, const ushort* __restrict__ Wch,
    ushort* __restrict__ dtb, const float* __restrict__ b_dt,
    float* __restrict__ bcb){
  __shared__ __align__(16) ushort lds[16384];
  int wg = xcd_swz();
  int row = wg / gridDim.x, col = wg % gridDim.x;
  gemm_body<3>(lds, xch, Wch, dtb, 1024, b_dt, bcb, row*64, col*64);
}

// ---------------- depthwise conv(K=3,pad=1) + silu -> bf16 ----------------
// input xzh [MMV][E2V] bf16; xx = cols [0,1024)
__global__ __launch_bounds__(256) void conv_silu_kernel(const ushort* __restrict__ xz,
        const float* __restrict__ cw, ushort* __restrict__ xch){
  int idx = blockIdx.x*256 + threadIdx.x;
  int d4  = idx & 255;
  int row = idx >> 8;
  int t = row & (LL-1);
  const ushort* p = xz + (size_t)row*E2V + d4*4;
  ushort4 u1 = *reinterpret_cast<const ushort4*>(p);
  ushort4 u0 = (t>0)    ? *reinterpret_cast<const ushort4*>(p - E2V) : make_ushort4(0,0,0,0);
  ushort4 u2 = (t<LL-1) ? *reinterpret_cast<const ushort4*>(p + E2V) : make_ushort4(0,0,0,0);
  int d = d4*4;
  float w[12];
  #pragma unroll
  for (int i=0;i<12;i++) w[i] = cw[d*3 + i];
  float4 o;
  o.x = bf2f(u0.x)*w[0] + bf2f(u1.x)*w[1]  + bf2f(u2.x)*w[2];
  o.y = bf2f(u0.y)*w[3] + bf2f(u1.y)*w[4]  + bf2f(u2.y)*w[5];
  o.z = bf2f(u0.z)*w[6] + bf2f(u1.z)*w[7]  + bf2f(u2.z)*w[8];
  o.w = bf2f(u0.w)*w[9] + bf2f(u1.w)*w[10] + bf2f(u2.w)*w[11];
  o.x = o.x / (1.f + __expf(-o.x));
  o.y = o.y / (1.f + __expf(-o.y));
  o.z = o.z / (1.f + __expf(-o.z));
  o.w = o.w / (1.f + __expf(-o.w));
  ushort4 H;
  H.x=f2bf(o.x); H.y=f2bf(o.y); H.z=f2bf(o.z); H.w=f2bf(o.w);
  *reinterpret_cast<ushort4*>(xch + (size_t)row*DIMV + d4*4) = H;
}

// ======== scan, one thread per channel d; S=16 state in registers ========
// F/P/E stored as bf16 (verified: absmax unchanged, R12).
__global__ __launch_bounds__(256) void scan_p1(const ushort* __restrict__ dt,
        const float* __restrict__ bc, const float* __restrict__ A_log,
        ushort* __restrict__ F, ushort* __restrict__ P){
  __shared__ float sB[CLEN*32];
  int bid = blockIdx.x;                 // b*(NCHUNK*4) + c*4 + dblk
  int dblk = bid & 3;
  int c  = (bid >> 2) & (NCHUNK-1);
  int b  = bid >> 8;
  int tid = threadIdx.x;
  int d = dblk*256 + tid;
  int row0 = b*LL + c*CLEN;
  ((float4*)sB)[tid] = *((const float4*)(bc + (size_t)row0*32) + tid);
  float a[16];
  {
    const float4* ap = (const float4*)(A_log + d*16);
    #pragma unroll
    for (int q=0;q<4;q++){
      float4 v = ap[q];
      a[q*4+0]=-__expf(v.x); a[q*4+1]=-__expf(v.y);
      a[q*4+2]=-__expf(v.z); a[q*4+3]=-__expf(v.w);
    }
  }
  __syncthreads();
  float st[16];
  #pragma unroll
  for (int s=0;s<16;s++) st[s]=0.f;
  float sdt = 0.f;
  const ushort* dtp = dt + (size_t)row0*DIMV + d;
  for (int t=0;t<CLEN;t++){
    float dtv = bf2f(dtp[(size_t)t*DIMV]);
    sdt += dtv;
    float4 B0 = *(const float4*)&sB[t*32+0];
    float4 B1 = *(const float4*)&sB[t*32+4];
    float4 B2 = *(const float4*)&sB[t*32+8];
    float4 B3 = *(const float4*)&sB[t*32+12];
    float Bv[16] = {B0.x,B0.y,B0.z,B0.w,B1.x,B1.y,B1.z,B1.w,
                    B2.x,B2.y,B2.z,B2.w,B3.x,B3.y,B3.z,B3.w};
    #pragma unroll
    for (int s=0;s<16;s++){
      float dA = __expf(dtv*a[s]);
      st[s] = fmaf(st[s], dA, dtv*Bv[s]);
    }
  }
  size_t o = ((size_t)((b*NCHUNK + c)*DIMV + d))*16;
  #pragma unroll
  for (int q=0;q<4;q++){
    ushort4 fv, pv;
    fv.x=f2bf(st[q*4]);   fv.y=f2bf(st[q*4+1]);
    fv.z=f2bf(st[q*4+2]); fv.w=f2bf(st[q*4+3]);
    pv.x=f2bf(__expf(sdt*a[q*4]));   pv.y=f2bf(__expf(sdt*a[q*4+1]));
    pv.z=f2bf(__expf(sdt*a[q*4+2])); pv.w=f2bf(__expf(sdt*a[q*4+3]));
    *(ushort4*)(F + o + q*4) = fv;
    *(ushort4*)(P + o + q*4) = pv;
  }
}

__global__ __launch_bounds__(256) void scan_p2(const ushort* __restrict__ F,
        const ushort* __restrict__ P, ushort* __restrict__ E){
  int idx = blockIdx.x*256 + threadIdx.x;   // BB*DIMV*SSV = 32768
  int b  = idx >> 14;
  int ds = idx & 16383;
  float e = 0.f;
  for (int c=0;c<NCHUNK;c++){
    size_t o = ((size_t)(b*NCHUNK + c) << 14) + ds;
    E[o] = f2bf(e);
    e = fmaf(bf2f(P[o]), e, bf2f(F[o]));
  }
}

__global__ __launch_bounds__(256) void scan_p3(const ushort* __restrict__ dt,
        const float* __restrict__ bc, const float* __restrict__ A_log,
        const ushort* __restrict__ E, const ushort* __restrict__ xch,
        const ushort* __restrict__ xz, const float* __restrict__ Dp,
        ushort* __restrict__ yh){
  __shared__ float sBC[CLEN*32];
  int bid = blockIdx.x;
  int dblk = bid & 3;
  int c  = (bid >> 2) & (NCHUNK-1);
  int b  = bid >> 8;
  int tid = threadIdx.x;
  int d = dblk*256 + tid;
  int row0 = b*LL + c*CLEN;
  ((float4*)sBC)[tid] = *((const float4*)(bc + (size_t)row0*32) + tid);
  float a[16];
  {
    const float4* ap = (const float4*)(A_log + d*16);
    #pragma unroll
    for (int q=0;q<4;q++){
      float4 v = ap[q];
      a[q*4+0]=-__expf(v.x); a[q*4+1]=-__expf(v.y);
      a[q*4+2]=-__expf(v.z); a[q*4+3]=-__expf(v.w);
    }
  }
  float st[16];
  {
    size_t o = ((size_t)((b*NCHUNK + c)*DIMV + d))*16;
    #pragma unroll
    for (int q=0;q<4;q++){
      ushort4 v = *(const ushort4*)(E + o + q*4);
      st[q*4]=bf2f(v.x); st[q*4+1]=bf2f(v.y); st[q*4+2]=bf2f(v.z); st[q*4+3]=bf2f(v.w);
    }
  }
  float Dv = Dp[d];
  __syncthreads();
  const ushort* dtp = dt + (size_t)row0*DIMV + d;
  for (int t=0;t<CLEN;t++){
    float dtv = bf2f(dtp[(size_t)t*DIMV]);
    float4 B0 = *(const float4*)&sBC[t*32+0];
    float4 B1 = *(const float4*)&sBC[t*32+4];
    float4 B2 = *(const float4*)&sBC[t*32+8];
    float4 B3 = *(const float4*)&sBC[t*32+12];
    float4 C0 = *(const float4*)&sBC[t*32+16];
    float4 C1 = *(const float4*)&sBC[t*32+20];
    float4 C2 = *(const float4*)&sBC[t*32+24];
    float4 C3 = *(const float4*)&sBC[t*32+28];
    float Bv[16] = {B0.x,B0.y,B0.z,B0.w,B1.x,B1.y,B1.z,B1.w,
                    B2.x,B2.y,B2.z,B2.w,B3.x,B3.y,B3.z,B3.w};
    float Cv[16] = {C0.x,C0.y,C0.z,C0.w,C1.x,C1.y,C1.z,C1.w,
                    C2.x,C2.y,C2.z,C2.w,C3.x,C3.y,C3.z,C3.w};
    float y = 0.f;
    #pragma unroll
    for (int s=0;s<16;s++){
      float dA = __expf(dtv*a[s]);
      st[s] = fmaf(st[s], dA, dtv*Bv[s]);
      y = fmaf(st[s], Cv[s], y);
    }
    int row = row0 + t;
    size_t ofs = (size_t)row*DIMV + d;
    float xcv = bf2f(xch[ofs]);
    float zv  = bf2f(xz[(size_t)row*E2V + INNERV + d]);
    float sz  = zv / (1.f + __expf(-zv));
    yh[ofs] = f2bf((y + Dv*xcv)*sz);
  }
}

extern "C" void kernel_launch(void* const* d_in, const int* in_sizes, int n_in,
                              void* d_out, int out_size, void* d_ws, size_t ws_size,
                              hipStream_t stream){
  const float* x     = (const float*)d_in[0];
  const float* gamma = (const float*)d_in[1];
  const float* beta  = (const float*)d_in[2];
  const float* W_in  = (const float*)d_in[3];
  const float* cw    = (const float*)d_in[4];
  const float* W_x   = (const float*)d_in[5];
  const float* W_dt  = (const float*)d_in[6];
  const float* b_dt  = (const float*)d_in[7];
  const float* A_log = (const float*)d_in[8];
  const float* Dp    = (const float*)d_in[9];
  const float* W_out = (const float*)d_in[10];
  float* out = (float*)d_out;
  float* ws  = (float*)d_ws;
  const size_t MB = (size_t)1 << 20;   // 1M floats
  // layout (float units); bf16 buffer of N elems occupies N/2 float slots.
  ushort* xzh = (ushort*)ws;                      // 8M bf16 -> [0,4M)
  ushort* hh  = (ushort*)(ws + 4*MB);             // [4M,6M)  dead after gemm0
  ushort* yh  = (ushort*)(ws + 4*MB);             // p3 writes (hh dead)
  ushort* xch = (ushort*)(ws + 6*MB);             // [6M,8M)
  ushort* dtb = (ushort*)(ws + 8*MB);             // [8M,10M)
  ushort* F   = (ushort*)(ws + 10*MB);            // [10M,11M)
  ushort* P   = (ushort*)(ws + 11*MB);            // [11M,12M)
  ushort* E   = (ushort*)(ws + 12*MB);            // [12M,13M)
  ushort* Wih = (ushort*)(ws + 13*MB);            // [13M,14M)  2M ushorts
  ushort* Wch = (ushort*)(ws + 14*MB);            // [14M,14.6M) 1152x1024 ushorts
  ushort* Woh = (ushort*)(ws + 14*MB + 640*1024); // [14.625M,15.125M)
  float*  bcb = ws + 15*MB + 256*1024;            // [15.25M, +128K floats)

  ln_init<<<4224 + MMV, 256, 0, stream>>>(x, gamma, beta, hh,
                                          W_in, W_dt, W_out, W_x,
                                          Wih, Wch, Woh);
  gemm_bf16<0><<<dim3(E2V/64, MMV/64), 256, 0, stream>>>(hh, Wih, xzh, E2V, nullptr);
  conv_silu_kernel<<<(MMV*(DIMV/4))/256, 256, 0, stream>>>(xzh, cw, xch);
  gemm_dtbc<<<dim3(18, MMV/64), 256, 0, stream>>>(xch, Wch, dtb, b_dt, bcb);
  scan_p1<<<BB*NCHUNK*(DIMV/256), 256, 0, stream>>>(dtb, bcb, A_log, F, P);
  scan_p2<<<(BB*DIMV*SSV)/256, 256, 0, stream>>>(F, P, E);
  scan_p3<<<BB*NCHUNK*(DIMV/256), 256, 0, stream>>>(dtb, bcb, A_log, E, xch, xzh, Dp, yh);
  gemm_bf16<2><<<dim3(DIMV/64, MMV/64), 256, 0, stream>>>(yh, Woh, out, DIMV, x);
}